// Round 4
// baseline (609.257 us; speedup 1.0000x reference)
//
#include <hip/hip_runtime.h>
#include <stdint.h>

// RelativePositionEncoding: out[i,j,:] = W[r1] + W[r2] + same_ent*W[132] + W[r4]
// r1/r2/r4 are bin indices from the 5 integer ids of tokens i and j.
// f32 in, f32 out. Memory-bound on the 537 MB f32 output write.
// W staged bit-exact as f32 in LDS (71 KB); ids packed 5x6-bit in LDS.

namespace {

constexpr int kDimIn  = 139;
constexpr int kDimOut = 128;   // f32 elems per output row
constexpr int kMaxTok = 1024;

__global__ __launch_bounds__(256)
void relpos_kernel(const float* __restrict__ feats,
                   const float* __restrict__ W,
                   float4* __restrict__ out, int n) {
  __shared__ __align__(16) float Wl[kDimIn * kDimOut];  // 71168 B
  __shared__ uint32_t ids[kMaxTok];                     // packed 5x6-bit ids

  const int tid = threadIdx.x;

  // ---- stage W (bit-exact f32 copy) ----
  for (int idx = tid; idx < kDimIn * kDimOut / 4; idx += 256)
    reinterpret_cast<float4*>(Wl)[idx] = reinterpret_cast<const float4*>(W)[idx];

  // ---- stage packed ids (res, tok, asym, ent, sym each in [0,64)) ----
  for (int j = tid; j < n; j += 256) {
    const float* fj = feats + (size_t)j * 10;
    uint32_t r = (uint32_t)(int)fj[0];
    uint32_t t = (uint32_t)(int)fj[1];
    uint32_t a = (uint32_t)(int)fj[2];
    uint32_t e = (uint32_t)(int)fj[3];
    uint32_t s = (uint32_t)(int)fj[4];
    ids[j] = r | (t << 6) | (a << 12) | (e << 18) | (s << 24);
  }
  __syncthreads();

  const int i = blockIdx.x;
  const uint32_t idi = ids[i];
  const int ri = idi & 63;
  const int ti = (idi >> 6) & 63;
  const int ai = (idi >> 12) & 63;
  const int ei = (idi >> 18) & 63;
  const int si = (idi >> 24) & 63;

  const int j_sub = tid >> 5;   // 8 j's per block-iteration
  const int col   = tid & 31;   // float4 column within the 128-wide row
  const float4* Wv = reinterpret_cast<const float4*>(Wl);  // row stride = 32 float4

  // hoist the entity row (132), loop-invariant
  const float4 w132 = Wv[132 * 32 + col];

  float4* orow = out + (size_t)i * n * 32 + col;
  for (int j0 = 0; j0 < n; j0 += 8) {
    const int j = j0 + j_sub;
    const uint32_t idj = ids[j];
    const int rj = idj & 63;
    const int tj = (idj >> 6) & 63;
    const int aj = (idj >> 12) & 63;
    const int ej = (idj >> 18) & 63;
    const int sj = (idj >> 24) & 63;

    const int dr  = ri - rj;
    const int dt  = ti - tj;
    const int dsm = si - sj;
    const bool sc = (ai == aj);                // same chain
    const float m = (ei == ej) ? 1.0f : 0.0f;  // same entity

    const int r1 = sc ? min(max(dr + 32, 0), 64) : 65;
    const int r2 = (sc && dr == 0) ? (66 + min(max(dt + 32, 0), 64)) : 131;
    const int r4 = sc ? 138 : (133 + min(max(dsm + 2, 0), 4));

    const float4 u1 = Wv[r1 * 32 + col];
    const float4 u2 = Wv[r2 * 32 + col];
    const float4 u4 = Wv[r4 * 32 + col];

    float4 o;
    o.x = fmaf(m, w132.x, u1.x + u2.x + u4.x);
    o.y = fmaf(m, w132.y, u1.y + u2.y + u4.y);
    o.z = fmaf(m, w132.z, u1.z + u2.z + u4.z);
    o.w = fmaf(m, w132.w, u1.w + u2.w + u4.w);

    orow[(size_t)j * 32] = o;
  }
}

}  // namespace

extern "C" void kernel_launch(void* const* d_in, const int* in_sizes, int n_in,
                              void* d_out, int out_size, void* d_ws, size_t ws_size,
                              hipStream_t stream) {
  const float* feats = (const float*)d_in[0];  // [1, n, 10] f32
  const float* W     = (const float*)d_in[1];  // [139, 128] f32
  int n = in_sizes[0] / 10;                    // b = 1
  if (n > kMaxTok) n = kMaxTok;                // reference fixes n = 1024
  relpos_kernel<<<n, 256, 0, stream>>>(feats, W, (float4*)d_out, n);
}

// Round 5
// 597.234 us; speedup vs baseline: 1.0201x; 1.0201x over previous
//
#include <hip/hip_runtime.h>
#include <stdint.h>

// RelativePositionEncoding: out[i,j,:] = W[r1] + W[r2] + m*W[132] + W[r4]
// f32 in / f32 out. Store-bound: 537 MB output write (floor ~85us @6.3TB/s).
// Round-5 structure: 512 thr/block (16 waves/CU), per-block precomputed
// packed row-indices rr[j], 2-way unrolled inner loop.

namespace {

constexpr int kDimIn  = 139;
constexpr int kDimOut = 128;   // f32 elems per output row
constexpr int kMaxTok = 1024;

__global__ __launch_bounds__(512)
void relpos_kernel(const float* __restrict__ feats,
                   const float* __restrict__ W,
                   float4* __restrict__ out, int n) {
  __shared__ __align__(16) float Wl[kDimIn * kDimOut];  // 71168 B
  __shared__ uint32_t ids[kMaxTok];                     // packed 5x6-bit ids
  __shared__ uint32_t rr[kMaxTok];                      // packed r1|r2|r4|m per j

  const int tid = threadIdx.x;
  const int i = blockIdx.x;

  // ---- stage W (bit-exact f32 copy) ----
  for (int idx = tid; idx < kDimIn * kDimOut / 4; idx += 512)
    reinterpret_cast<float4*>(Wl)[idx] = reinterpret_cast<const float4*>(W)[idx];

  // ---- stage packed ids (res, tok, asym, ent, sym each in [0,64)) ----
  for (int j = tid; j < n; j += 512) {
    const float* fj = feats + (size_t)j * 10;
    uint32_t r = (uint32_t)(int)fj[0];
    uint32_t t = (uint32_t)(int)fj[1];
    uint32_t a = (uint32_t)(int)fj[2];
    uint32_t e = (uint32_t)(int)fj[3];
    uint32_t s = (uint32_t)(int)fj[4];
    ids[j] = r | (t << 6) | (a << 12) | (e << 18) | (s << 24);
  }
  __syncthreads();

  // ---- precompute packed W-row indices for this block's i ----
  {
    const uint32_t idi = ids[i];
    const int ri = idi & 63;
    const int ti = (idi >> 6) & 63;
    const int ai = (idi >> 12) & 63;
    const int ei = (idi >> 18) & 63;
    const int si = (idi >> 24) & 63;
    for (int j = tid; j < n; j += 512) {
      const uint32_t idj = ids[j];
      const int dr  = ri - (int)(idj & 63);
      const int dt  = ti - (int)((idj >> 6) & 63);
      const int dsm = si - (int)((idj >> 24) & 63);
      const bool sc = (ai == (int)((idj >> 12) & 63));
      const uint32_t m = (ei == (int)((idj >> 18) & 63)) ? 1u : 0u;
      const uint32_t r1 = sc ? (uint32_t)min(max(dr + 32, 0), 64) : 65u;
      const uint32_t r2 = (sc && dr == 0)
                              ? (uint32_t)(66 + min(max(dt + 32, 0), 64)) : 131u;
      const uint32_t r4 = sc ? 138u : (uint32_t)(133 + min(max(dsm + 2, 0), 4));
      rr[j] = r1 | (r2 << 8) | (r4 << 16) | (m << 24);
    }
  }
  __syncthreads();

  const int j_sub = tid >> 5;   // [0,16): 16 j's per unroll-half
  const int col   = tid & 31;   // float4 column within the 128-wide row
  const float4* Wv = reinterpret_cast<const float4*>(Wl);  // row stride 32 f4

  const float4 w132 = Wv[132 * 32 + col];

  float4* orow = out + (size_t)i * n * 32 + col;
  for (int j0 = 0; j0 < n; j0 += 32) {
    const int ja = j0 + j_sub;
    const int jb = ja + 16;
    const uint32_t qa = rr[ja];
    const uint32_t qb = rr[jb];

    const float4 a1 = Wv[(qa & 255u) * 32 + col];
    const float4 b1 = Wv[(qb & 255u) * 32 + col];
    const float4 a2 = Wv[((qa >> 8) & 255u) * 32 + col];
    const float4 b2 = Wv[((qb >> 8) & 255u) * 32 + col];
    const float4 a4 = Wv[((qa >> 16) & 255u) * 32 + col];
    const float4 b4 = Wv[((qb >> 16) & 255u) * 32 + col];
    const float ma = (float)(qa >> 24);
    const float mb = (float)(qb >> 24);

    float4 oa, ob;
    oa.x = fmaf(ma, w132.x, a1.x + a2.x + a4.x);
    oa.y = fmaf(ma, w132.y, a1.y + a2.y + a4.y);
    oa.z = fmaf(ma, w132.z, a1.z + a2.z + a4.z);
    oa.w = fmaf(ma, w132.w, a1.w + a2.w + a4.w);
    ob.x = fmaf(mb, w132.x, b1.x + b2.x + b4.x);
    ob.y = fmaf(mb, w132.y, b1.y + b2.y + b4.y);
    ob.z = fmaf(mb, w132.z, b1.z + b2.z + b4.z);
    ob.w = fmaf(mb, w132.w, b1.w + b2.w + b4.w);

    orow[(size_t)ja * 32] = oa;
    orow[(size_t)jb * 32] = ob;
  }
}

}  // namespace

extern "C" void kernel_launch(void* const* d_in, const int* in_sizes, int n_in,
                              void* d_out, int out_size, void* d_ws, size_t ws_size,
                              hipStream_t stream) {
  const float* feats = (const float*)d_in[0];  // [1, n, 10] f32
  const float* W     = (const float*)d_in[1];  // [139, 128] f32
  int n = in_sizes[0] / 10;                    // b = 1
  if (n > kMaxTok) n = kMaxTok;                // reference fixes n = 1024
  relpos_kernel<<<n, 512, 0, stream>>>(feats, W, (float4*)d_out, n);
}

// Round 6
// 527.738 us; speedup vs baseline: 1.1545x; 1.1317x over previous
//
#include <hip/hip_runtime.h>
#include <stdint.h>

// RelativePositionEncoding: out[i,j,:] = W[r1] + W[r2] + m*W[132] + W[r4]
// f32 in / f32 out. Store-bound: 537 MB output write (floor ~87us @6.2TB/s).
// Round-6: ~98% of pairs are different-chain -> output is one of 10 rows
// combo[c,m] = W[65]+W[131]+W[133+c]+m*W[132], precomputed in LDS (5KB).
// Common path: 1 ds_read_b32 + 1 ds_read_b128 + 1 store. Rare same-chain
// path gathers 3 W rows from L1/L2. LDS 9.2KB -> 4 blocks/CU, 32 waves/CU.

namespace {

constexpr int kMaxTok = 1024;

__global__ __launch_bounds__(512)
void relpos_kernel(const float* __restrict__ feats,
                   const float* __restrict__ W,
                   float4* __restrict__ out, int n) {
  __shared__ uint32_t rr[kMaxTok];                 // packed row-spec per j
  __shared__ __align__(16) float combo[10][128];   // 10 precomputed rows, 5 KB

  const int tid = threadIdx.x;
  const int i = blockIdx.x;

  // ---- ids of token i (block-uniform; L1 broadcast loads) ----
  const float* fi = feats + (size_t)i * 10;
  const int ri = (int)fi[0];
  const int ti = (int)fi[1];
  const int ai = (int)fi[2];
  const int ei = (int)fi[3];
  const int si = (int)fi[4];

  // ---- per-j packed spec ----
  for (int j = tid; j < n; j += 512) {
    const float* fj = feats + (size_t)j * 10;
    const int rj = (int)fj[0];
    const int tj = (int)fj[1];
    const int aj = (int)fj[2];
    const int ej = (int)fj[3];
    const int sj = (int)fj[4];
    const uint32_t m = (ei == ej) ? 1u : 0u;
    if (ai == aj) {  // same chain (rare): full 3-row spec, r4 = 138
      const int dr = ri - rj;
      const uint32_t r1 = (uint32_t)min(max(dr + 32, 0), 64);
      const uint32_t r2 = (dr == 0)
                              ? (uint32_t)(66 + min(max(ti - tj + 32, 0), 64))
                              : 131u;
      rr[j] = r1 | (r2 << 8) | (m << 24);
    } else {         // diff chain (common): combo row index + tag bit
      const uint32_t c = (uint32_t)min(max(si - sj + 2, 0), 4);
      rr[j] = 0x80000000u | (c * 2u + m);
    }
  }

  // ---- precompute the 10 diff-chain rows into LDS ----
  if (tid < 320) {
    const int row = tid >> 5;   // 0..9  (= c*2 + m)
    const int col = tid & 31;
    const int c = row >> 1;
    const float mm = (float)(row & 1);
    const float4* Wg = reinterpret_cast<const float4*>(W);
    const float4 u1 = Wg[65 * 32 + col];
    const float4 u2 = Wg[131 * 32 + col];
    const float4 u4 = Wg[(133 + c) * 32 + col];
    const float4 um = Wg[132 * 32 + col];
    float4 o;
    o.x = fmaf(mm, um.x, u1.x + u2.x + u4.x);
    o.y = fmaf(mm, um.y, u1.y + u2.y + u4.y);
    o.z = fmaf(mm, um.z, u1.z + u2.z + u4.z);
    o.w = fmaf(mm, um.w, u1.w + u2.w + u4.w);
    reinterpret_cast<float4*>(combo[row])[col] = o;
  }
  __syncthreads();

  const int j_sub = tid >> 5;   // 16 j's per iteration
  const int col   = tid & 31;   // float4 column within the 128-wide row
  const float4* Wg = reinterpret_cast<const float4*>(W);
  const float4* Cv = reinterpret_cast<const float4*>(combo);

  // hoist W[132] (needed by rare path) into registers — 1 L1 load
  const float4 w132 = Wg[132 * 32 + col];

  float4* orow = out + (size_t)i * n * 32 + col;
  for (int j0 = 0; j0 < n; j0 += 16) {
    const int j = j0 + j_sub;
    const uint32_t q = rr[j];
    float4 o;
    if (q & 0x80000000u) {
      o = Cv[(q & 15u) * 32 + col];            // 1 LDS b128 read
    } else {
      const float4 u1 = Wg[(q & 255u) * 32 + col];          // L1/L2
      const float4 u2 = Wg[((q >> 8) & 255u) * 32 + col];
      const float4 u4 = Wg[138 * 32 + col];
      const float mm = (float)(q >> 24);
      o.x = fmaf(mm, w132.x, u1.x + u2.x + u4.x);
      o.y = fmaf(mm, w132.y, u1.y + u2.y + u4.y);
      o.z = fmaf(mm, w132.z, u1.z + u2.z + u4.z);
      o.w = fmaf(mm, w132.w, u1.w + u2.w + u4.w);
    }
    orow[(size_t)j * 32] = o;
  }
}

}  // namespace

extern "C" void kernel_launch(void* const* d_in, const int* in_sizes, int n_in,
                              void* d_out, int out_size, void* d_ws, size_t ws_size,
                              hipStream_t stream) {
  const float* feats = (const float*)d_in[0];  // [1, n, 10] f32
  const float* W     = (const float*)d_in[1];  // [139, 128] f32
  int n = in_sizes[0] / 10;                    // b = 1
  if (n > kMaxTok) n = kMaxTok;                // reference fixes n = 1024
  relpos_kernel<<<n, 512, 0, stream>>>(feats, W, (float4*)d_out, n);
}

// Round 9
// 525.067 us; speedup vs baseline: 1.1603x; 1.0051x over previous
//
#include <hip/hip_runtime.h>
#include <stdint.h>

// RelativePositionEncoding: out[i,j,:] = W[r1] + W[r2] + m*W[132] + W[r4]
// f32 in / f32 out. Store-bound: 537 MB output write (floor ~86us @6.25TB/s).
// Round-8: round-6 structure (10 precomputed diff-chain combo rows in LDS,
// rare same-chain path from L1/L2) + non-temporal stores (via clang native
// vector type — HIP float4 is rejected by the builtin) + 2-way unroll.

namespace {

constexpr int kMaxTok = 1024;

typedef float f32x4 __attribute__((ext_vector_type(4)));

__global__ __launch_bounds__(512)
void relpos_kernel(const float* __restrict__ feats,
                   const float* __restrict__ W,
                   float4* __restrict__ out, int n) {
  __shared__ uint32_t rr[kMaxTok];                 // packed row-spec per j
  __shared__ __align__(16) float combo[10][128];   // 10 precomputed rows, 5 KB

  const int tid = threadIdx.x;
  const int i = blockIdx.x;

  // ---- ids of token i (block-uniform; L1 broadcast loads) ----
  const float* fi = feats + (size_t)i * 10;
  const int ri = (int)fi[0];
  const int ti = (int)fi[1];
  const int ai = (int)fi[2];
  const int ei = (int)fi[3];
  const int si = (int)fi[4];

  // ---- per-j packed spec ----
  for (int j = tid; j < n; j += 512) {
    const float* fj = feats + (size_t)j * 10;
    const int rj = (int)fj[0];
    const int tj = (int)fj[1];
    const int aj = (int)fj[2];
    const int ej = (int)fj[3];
    const int sj = (int)fj[4];
    const uint32_t m = (ei == ej) ? 1u : 0u;
    if (ai == aj) {  // same chain (rare): full 3-row spec, r4 = 138
      const int dr = ri - rj;
      const uint32_t r1 = (uint32_t)min(max(dr + 32, 0), 64);
      const uint32_t r2 = (dr == 0)
                              ? (uint32_t)(66 + min(max(ti - tj + 32, 0), 64))
                              : 131u;
      rr[j] = r1 | (r2 << 8) | (m << 24);
    } else {         // diff chain (common): combo row index + tag bit
      const uint32_t c = (uint32_t)min(max(si - sj + 2, 0), 4);
      rr[j] = 0x80000000u | (c * 2u + m);
    }
  }

  // ---- precompute the 10 diff-chain rows into LDS ----
  if (tid < 320) {
    const int row = tid >> 5;   // 0..9  (= c*2 + m)
    const int col = tid & 31;
    const int c = row >> 1;
    const float mm = (float)(row & 1);
    const float4* Wg = reinterpret_cast<const float4*>(W);
    const float4 u1 = Wg[65 * 32 + col];
    const float4 u2 = Wg[131 * 32 + col];
    const float4 u4 = Wg[(133 + c) * 32 + col];
    const float4 um = Wg[132 * 32 + col];
    float4 o;
    o.x = fmaf(mm, um.x, u1.x + u2.x + u4.x);
    o.y = fmaf(mm, um.y, u1.y + u2.y + u4.y);
    o.z = fmaf(mm, um.z, u1.z + u2.z + u4.z);
    o.w = fmaf(mm, um.w, u1.w + u2.w + u4.w);
    reinterpret_cast<float4*>(combo[row])[col] = o;
  }
  __syncthreads();

  const int j_sub = tid >> 5;   // [0,16)
  const int col   = tid & 31;   // float4 column within the 128-wide row
  const float4* Wg = reinterpret_cast<const float4*>(W);
  const float4* Cv = reinterpret_cast<const float4*>(combo);

  // hoisted rows for the rare path (register-resident, 2 L1 loads)
  const float4 w132 = Wg[132 * 32 + col];
  const float4 w138 = Wg[138 * 32 + col];

  f32x4* orow = reinterpret_cast<f32x4*>(out + (size_t)i * n * 32 + col);

  auto resolve = [&](uint32_t q) -> f32x4 {
    f32x4 o;
    if (q & 0x80000000u) {
      const float4 c4 = Cv[(q & 15u) * 32 + col];  // 1 LDS b128 read
      o[0] = c4.x; o[1] = c4.y; o[2] = c4.z; o[3] = c4.w;
    } else {
      const float4 u1 = Wg[(q & 255u) * 32 + col];          // L1/L2
      const float4 u2 = Wg[((q >> 8) & 255u) * 32 + col];
      const float mm = (float)(q >> 24);
      o[0] = fmaf(mm, w132.x, u1.x + u2.x + w138.x);
      o[1] = fmaf(mm, w132.y, u1.y + u2.y + w138.y);
      o[2] = fmaf(mm, w132.z, u1.z + u2.z + w138.z);
      o[3] = fmaf(mm, w132.w, u1.w + u2.w + w138.w);
    }
    return o;
  };

  for (int j0 = 0; j0 < n; j0 += 32) {
    const int ja = j0 + j_sub;
    const int jb = ja + 16;
    const uint32_t qa = rr[ja];
    const uint32_t qb = rr[jb];
    const f32x4 oa = resolve(qa);
    const f32x4 ob = resolve(qb);
    __builtin_nontemporal_store(oa, orow + (size_t)ja * 32);
    __builtin_nontemporal_store(ob, orow + (size_t)jb * 32);
  }
}

}  // namespace

extern "C" void kernel_launch(void* const* d_in, const int* in_sizes, int n_in,
                              void* d_out, int out_size, void* d_ws, size_t ws_size,
                              hipStream_t stream) {
  const float* feats = (const float*)d_in[0];  // [1, n, 10] f32
  const float* W     = (const float*)d_in[1];  // [139, 128] f32
  int n = in_sizes[0] / 10;                    // b = 1
  if (n > kMaxTok) n = kMaxTok;                // reference fixes n = 1024
  relpos_kernel<<<n, 512, 0, stream>>>(feats, W, (float4*)d_out, n);
}